// Round 1
// baseline (260.932 us; speedup 1.0000x reference)
//
#include <hip/hip_runtime.h>
#include <hip/hip_bf16.h>
#include <stdint.h>

typedef __hip_bfloat16 bf16;
typedef __attribute__((ext_vector_type(8))) short bf16x8;
typedef __attribute__((ext_vector_type(4))) float f32x4;

#define MFMA16(a,b,c) __builtin_amdgcn_mfma_f32_16x16x32_bf16((a),(b),(c),0,0,0)

#define B_ 2
#define T_ 2048
#define E_ 1024
#define H_ 16
#define D_ 64
#define M_ (B_*T_)   // 4096

__device__ __forceinline__ void gload_lds16(const bf16* g, bf16* l) {
  __builtin_amdgcn_global_load_lds(
      (const __attribute__((address_space(1))) unsigned int*)g,
      (__attribute__((address_space(3))) unsigned int*)l,
      16, 0, 0);
}

// ---------------- pre-pass: f32 -> bf16 convert ----------------
__global__ __launch_bounds__(256) void cvt_x_kernel(const float* __restrict__ in,
                                                    bf16* __restrict__ out) {
  int i = blockIdx.x * 256 + threadIdx.x;        // each thread: 4 floats
  float4 v = reinterpret_cast<const float4*>(in)[i];
  union { bf16 h[4]; unsigned long long u; } t;
  t.h[0] = __float2bfloat16(v.x);
  t.h[1] = __float2bfloat16(v.y);
  t.h[2] = __float2bfloat16(v.z);
  t.h[3] = __float2bfloat16(v.w);
  reinterpret_cast<unsigned long long*>(out)[i] = t.u;
}

// ---------------- pre-pass: W [K][N] f32 -> Wt [N][K] bf16 ----------------
__global__ __launch_bounds__(256) void transpose_cvt_kernel(const float* __restrict__ W,
                                                            bf16* __restrict__ Wt) {
  __shared__ float tile[32][33];
  const int tx = threadIdx.x, ty = threadIdx.y;  // 32 x 8
  const int n0 = blockIdx.x * 32, k0 = blockIdx.y * 32;
#pragma unroll
  for (int i = 0; i < 4; i++)
    tile[ty + 8*i][tx] = W[(size_t)(k0 + ty + 8*i) * E_ + n0 + tx];
  __syncthreads();
#pragma unroll
  for (int i = 0; i < 4; i++)
    Wt[(size_t)(n0 + ty + 8*i) * E_ + k0 + tx] = __float2bfloat16(tile[tx][ty + 8*i]);
}

// ---------------- GEMM: C[M=4096][N=1024] = A[M][K] * Bt[N][K]^T ----------------
// mode 0: write bf16 to [B,H,T,D] (Q with scale, K with scale=1)
// mode 1: write bf16 to [B,H,D,T] (V transposed)
// mode 2: write f32 + bias to row-major [M][N] (final output)
__global__ __launch_bounds__(256) void gemm_bt_kernel(
    const bf16* __restrict__ A, const bf16* __restrict__ Bt,
    void* __restrict__ out, const float* __restrict__ bias,
    const int mode, const float scale)
{
  constexpr int K = E_;
  __shared__ __align__(16) bf16 As[128*32];
  __shared__ __align__(16) bf16 Bs[128*32];
  const int tid = threadIdx.x;
  const int w = tid >> 6, l = tid & 63;
  const int lc = l & 15, lr = l >> 4;
  const int m0 = blockIdx.y * 128, n0 = blockIdx.x * 128;
  const int wr = (w >> 1) * 64, wc = (w & 1) * 64;

  f32x4 acc[4][4];
#pragma unroll
  for (int m = 0; m < 4; m++)
#pragma unroll
    for (int n = 0; n < 4; n++) acc[m][n] = (f32x4)0.0f;

  const int srow = l >> 2;            // 0..15
  const int scol = (l & 3) * 8;       // k element offset

  for (int k0 = 0; k0 < K; k0 += 32) {
#pragma unroll
    for (int p = 0; p < 2; p++) {
      const int r = (w*2 + p) * 16 + srow;
      gload_lds16(A  + (size_t)(m0 + r) * K + k0 + scol, &As[(w*2 + p) * 512]);
      gload_lds16(Bt + (size_t)(n0 + r) * K + k0 + scol, &Bs[(w*2 + p) * 512]);
    }
    __syncthreads();
    bf16x8 af[4], bfr[4];
#pragma unroll
    for (int m = 0; m < 4; m++)
      af[m] = *reinterpret_cast<const bf16x8*>(&As[(wr + m*16 + lc) * 32 + lr * 8]);
#pragma unroll
    for (int n = 0; n < 4; n++)
      bfr[n] = *reinterpret_cast<const bf16x8*>(&Bs[(wc + n*16 + lc) * 32 + lr * 8]);
#pragma unroll
    for (int m = 0; m < 4; m++)
#pragma unroll
      for (int n = 0; n < 4; n++)
        acc[m][n] = MFMA16(af[m], bfr[n], acc[m][n]);
    __syncthreads();
  }

#pragma unroll
  for (int m = 0; m < 4; m++) {
#pragma unroll
    for (int n = 0; n < 4; n++) {
#pragma unroll
      for (int j = 0; j < 4; j++) {
        const int row = m0 + wr + m*16 + lr*4 + j;   // token index
        const int col = n0 + wc + n*16 + lc;         // output feature
        const float v = acc[m][n][j] * scale;
        if (mode == 2) {
          reinterpret_cast<float*>(out)[(size_t)row * E_ + col] = v + bias[col];
        } else {
          const int b = row >> 11, t = row & (T_-1);
          const int h = col >> 6,  d = col & (D_-1);
          size_t idx;
          if (mode == 0) idx = (((size_t)(b*H_ + h)) * T_ + t) * D_ + d;
          else           idx = (((size_t)(b*H_ + h)) * D_ + d) * T_ + t;
          reinterpret_cast<bf16*>(out)[idx] = __float2bfloat16(v);
        }
      }
    }
  }
}

// ---------------- flash attention (causal) ----------------
// Q,K: [B*H][T][D] bf16 (Q pre-scaled by D^-0.5). Vt: [B*H][D][T] bf16.
// O: [B*T][E] bf16.  Grid: (16 qblocks, 32 bh). Block: 256 = 4 waves x 32 q-rows.
__global__ __launch_bounds__(256) void attn_fwd_kernel(
    const bf16* __restrict__ Q, const bf16* __restrict__ Kt,
    const bf16* __restrict__ Vt, bf16* __restrict__ O)
{
  __shared__ __align__(16) bf16 P[4][32 * 80];   // per-wave P tile, padded stride 80
  const int tid = threadIdx.x;
  const int w = tid >> 6, l = tid & 63;
  const int lc = l & 15, lr = l >> 4;
  const int bh = blockIdx.y;                 // b*16 + h
  const int bq = blockIdx.x * 128 + w * 32;  // wave q base

  const bf16* Qb = Q  + (size_t)bh * T_ * D_;
  const bf16* Kb = Kt + (size_t)bh * T_ * D_;
  const bf16* Vb = Vt + (size_t)bh * D_ * T_;

  // Q fragments (held across the k loop)
  bf16x8 qf[2][2];
#pragma unroll
  for (int m = 0; m < 2; m++)
#pragma unroll
    for (int kk = 0; kk < 2; kk++)
      qf[m][kk] = *reinterpret_cast<const bf16x8*>(
          &Qb[(size_t)(bq + m*16 + lc) * D_ + kk*32 + lr*8]);

  f32x4 oacc[2][4];
  float mrow[2][4], lrow[2][4];
#pragma unroll
  for (int m = 0; m < 2; m++)
#pragma unroll
    for (int n = 0; n < 4; n++) oacc[m][n] = (f32x4)0.0f;
#pragma unroll
  for (int m = 0; m < 2; m++)
#pragma unroll
    for (int j = 0; j < 4; j++) { mrow[m][j] = -1e30f; lrow[m][j] = 0.0f; }

  const int nkt = ((bq + 31) >> 6) + 1;
  for (int kt = 0; kt < nkt; kt++) {
    const int kbase = kt * 64;
    // ---- S = Q K^T ----
    f32x4 s[2][4];
#pragma unroll
    for (int m = 0; m < 2; m++)
#pragma unroll
      for (int n = 0; n < 4; n++) s[m][n] = (f32x4)0.0f;
    bf16x8 kf[4][2];
#pragma unroll
    for (int n = 0; n < 4; n++)
#pragma unroll
      for (int kk = 0; kk < 2; kk++)
        kf[n][kk] = *reinterpret_cast<const bf16x8*>(
            &Kb[(size_t)(kbase + n*16 + lc) * D_ + kk*32 + lr*8]);
#pragma unroll
    for (int m = 0; m < 2; m++)
#pragma unroll
      for (int n = 0; n < 4; n++)
#pragma unroll
        for (int kk = 0; kk < 2; kk++)
          s[m][n] = MFMA16(qf[m][kk], kf[n][kk], s[m][n]);

    // ---- causal mask (scale already folded into Q) ----
    const bool need_mask = (kbase + 63 > bq);
    if (need_mask) {
#pragma unroll
      for (int m = 0; m < 2; m++)
#pragma unroll
        for (int n = 0; n < 4; n++)
#pragma unroll
          for (int j = 0; j < 4; j++) {
            const int q = bq + m*16 + lr*4 + j;
            const int k = kbase + n*16 + lc;
            if (k > q) s[m][n][j] = -1e30f;
          }
    }

    // ---- row max (over 4 n-frags, then across 16 lanes) ----
    float pmax[2][4];
#pragma unroll
    for (int m = 0; m < 2; m++)
#pragma unroll
      for (int j = 0; j < 4; j++) {
        float v = fmaxf(fmaxf(s[0+m*0][0][j], s[m][1][j]), fmaxf(s[m][2][j], s[m][3][j]));
        v = fmaxf(v, s[m][0][j]);
        pmax[m][j] = v;
      }
#pragma unroll
    for (int d = 1; d < 16; d <<= 1)
#pragma unroll
      for (int m = 0; m < 2; m++)
#pragma unroll
        for (int j = 0; j < 4; j++)
          pmax[m][j] = fmaxf(pmax[m][j], __shfl_xor(pmax[m][j], d));

    // ---- online softmax update ----
    float fsc[2][4];
#pragma unroll
    for (int m = 0; m < 2; m++)
#pragma unroll
      for (int j = 0; j < 4; j++) {
        const float mn = fmaxf(mrow[m][j], pmax[m][j]);
        fsc[m][j] = exp2f((mrow[m][j] - mn) * 1.44269504f);
        mrow[m][j] = mn;
      }
    float psum[2][4];
#pragma unroll
    for (int m = 0; m < 2; m++)
#pragma unroll
      for (int j = 0; j < 4; j++) psum[m][j] = 0.0f;
#pragma unroll
    for (int m = 0; m < 2; m++)
#pragma unroll
      for (int n = 0; n < 4; n++)
#pragma unroll
        for (int j = 0; j < 4; j++) {
          const float p = exp2f((s[m][n][j] - mrow[m][j]) * 1.44269504f);
          s[m][n][j] = p;
          psum[m][j] += p;
        }
#pragma unroll
    for (int d = 1; d < 16; d <<= 1)
#pragma unroll
      for (int m = 0; m < 2; m++)
#pragma unroll
        for (int j = 0; j < 4; j++)
          psum[m][j] += __shfl_xor(psum[m][j], d);
#pragma unroll
    for (int m = 0; m < 2; m++)
#pragma unroll
      for (int j = 0; j < 4; j++)
        lrow[m][j] = lrow[m][j] * fsc[m][j] + psum[m][j];
#pragma unroll
    for (int m = 0; m < 2; m++)
#pragma unroll
      for (int n = 0; n < 4; n++)
#pragma unroll
        for (int j = 0; j < 4; j++)
          oacc[m][n][j] *= fsc[m][j];

    // ---- P -> LDS (per-wave private, no barrier needed) ----
#pragma unroll
    for (int m = 0; m < 2; m++)
#pragma unroll
      for (int n = 0; n < 4; n++)
#pragma unroll
        for (int j = 0; j < 4; j++)
          P[w][(m*16 + lr*4 + j) * 80 + n*16 + lc] = __float2bfloat16(s[m][n][j]);

    // ---- O += P V ----
#pragma unroll
    for (int kk = 0; kk < 2; kk++) {
      bf16x8 pa0 = *reinterpret_cast<const bf16x8*>(&P[w][(lc) * 80 + kk*32 + lr*8]);
      bf16x8 pa1 = *reinterpret_cast<const bf16x8*>(&P[w][(16 + lc) * 80 + kk*32 + lr*8]);
#pragma unroll
      for (int n = 0; n < 4; n++) {
        bf16x8 vf = *reinterpret_cast<const bf16x8*>(
            &Vb[(size_t)(n*16 + lc) * T_ + kbase + kk*32 + lr*8]);
        oacc[0][n] = MFMA16(pa0, vf, oacc[0][n]);
        oacc[1][n] = MFMA16(pa1, vf, oacc[1][n]);
      }
    }
  }

  // ---- epilogue: O[b*T + q][h*64 + d] ----
  const int b = bh >> 4, h = bh & 15;
#pragma unroll
  for (int m = 0; m < 2; m++)
#pragma unroll
    for (int j = 0; j < 4; j++) {
      const float inv = 1.0f / lrow[m][j];
      const int row = b * T_ + bq + m*16 + lr*4 + j;
#pragma unroll
      for (int n = 0; n < 4; n++) {
        const int col = h * 64 + n*16 + lc;
        O[(size_t)row * E_ + col] = __float2bfloat16(oacc[m][n][j] * inv);
      }
    }
}

// ---------------- launch ----------------
extern "C" void kernel_launch(void* const* d_in, const int* in_sizes, int n_in,
                              void* d_out, int out_size, void* d_ws, size_t ws_size,
                              hipStream_t stream) {
  const float* x  = (const float*)d_in[0];
  const float* Wq = (const float*)d_in[1];
  const float* Wk = (const float*)d_in[2];
  const float* Wv = (const float*)d_in[3];
  const float* Wo = (const float*)d_in[4];
  const float* bo = (const float*)d_in[5];
  float* out = (float*)d_out;

  char* ws = (char*)d_ws;
  bf16* xb  = (bf16*)(ws);                         // 8 MB  [4096][1024]
  bf16* WqT = (bf16*)(ws + (8ull  << 20));         // 2 MB  [N][K]
  bf16* WkT = (bf16*)(ws + (10ull << 20));
  bf16* WvT = (bf16*)(ws + (12ull << 20));
  bf16* WoT = (bf16*)(ws + (14ull << 20));
  bf16* Qb  = (bf16*)(ws + (16ull << 20));         // 8 MB  [BH][T][D]
  bf16* Kb  = (bf16*)(ws + (24ull << 20));         // 8 MB  [BH][T][D]
  bf16* Vtb = (bf16*)(ws + (32ull << 20));         // 8 MB  [BH][D][T]
  bf16* Ob  = (bf16*)(ws + (40ull << 20));         // 8 MB  [4096][1024]

  cvt_x_kernel<<<4096, 256, 0, stream>>>(x, xb);
  dim3 tb(32, 8);
  dim3 tg(32, 32);
  transpose_cvt_kernel<<<tg, tb, 0, stream>>>(Wq, WqT);
  transpose_cvt_kernel<<<tg, tb, 0, stream>>>(Wk, WkT);
  transpose_cvt_kernel<<<tg, tb, 0, stream>>>(Wv, WvT);
  transpose_cvt_kernel<<<tg, tb, 0, stream>>>(Wo, WoT);

  dim3 gg(8, 32);  // N tiles x M tiles
  gemm_bt_kernel<<<gg, 256, 0, stream>>>(xb, WqT, Qb,  nullptr, 0, 0.125f); // Q * D^-0.5
  gemm_bt_kernel<<<gg, 256, 0, stream>>>(xb, WkT, Kb,  nullptr, 0, 1.0f);
  gemm_bt_kernel<<<gg, 256, 0, stream>>>(xb, WvT, Vtb, nullptr, 1, 1.0f);

  attn_fwd_kernel<<<dim3(16, 32), 256, 0, stream>>>(Qb, Kb, Vtb, Ob);

  gemm_bt_kernel<<<gg, 256, 0, stream>>>(Ob, WoT, out, bo, 2, 1.0f);
}

// Round 2
// 229.095 us; speedup vs baseline: 1.1390x; 1.1390x over previous
//
#include <hip/hip_runtime.h>
#include <hip/hip_bf16.h>
#include <stdint.h>

typedef __hip_bfloat16 bf16;
typedef __attribute__((ext_vector_type(8))) short bf16x8;
typedef __attribute__((ext_vector_type(4))) float f32x4;

#define MFMA16(a,b,c) __builtin_amdgcn_mfma_f32_16x16x32_bf16((a),(b),(c),0,0,0)

#define B_ 2
#define T_ 2048
#define E_ 1024
#define H_ 16
#define D_ 64
#define M_ (B_*T_)   // 4096
#define PROJ_ELEMS (32ull * 2048ull * 64ull)   // 4.19M elems per Q/K/V tensor

__device__ __forceinline__ void gload_lds16(const bf16* g, bf16* l) {
  __builtin_amdgcn_global_load_lds(
      (const __attribute__((address_space(1))) unsigned int*)g,
      (__attribute__((address_space(3))) unsigned int*)l,
      16, 0, 0);
}

// ---------------- pre-pass: f32 -> bf16 convert ----------------
__global__ __launch_bounds__(256) void cvt_x_kernel(const float* __restrict__ in,
                                                    bf16* __restrict__ out) {
  int i = blockIdx.x * 256 + threadIdx.x;        // each thread: 4 floats
  float4 v = reinterpret_cast<const float4*>(in)[i];
  union { bf16 h[4]; unsigned long long u; } t;
  t.h[0] = __float2bfloat16(v.x);
  t.h[1] = __float2bfloat16(v.y);
  t.h[2] = __float2bfloat16(v.z);
  t.h[3] = __float2bfloat16(v.w);
  reinterpret_cast<unsigned long long*>(out)[i] = t.u;
}

// ---------------- pre-pass: 4x W [K][N] f32 -> Wt [N][K] bf16 (fused) ----------------
__global__ __launch_bounds__(256) void transpose_cvt4_kernel(
    const float* __restrict__ W0, const float* __restrict__ W1,
    const float* __restrict__ W2, const float* __restrict__ W3,
    bf16* __restrict__ T0, bf16* __restrict__ T1,
    bf16* __restrict__ T2, bf16* __restrict__ T3) {
  __shared__ float tile[32][33];
  const float* W; bf16* Wt;
  switch (blockIdx.z) {
    case 0: W = W0; Wt = T0; break;
    case 1: W = W1; Wt = T1; break;
    case 2: W = W2; Wt = T2; break;
    default: W = W3; Wt = T3; break;
  }
  const int tx = threadIdx.x, ty = threadIdx.y;  // 32 x 8
  const int n0 = blockIdx.x * 32, k0 = blockIdx.y * 32;
#pragma unroll
  for (int i = 0; i < 4; i++)
    tile[ty + 8*i][tx] = W[(size_t)(k0 + ty + 8*i) * E_ + n0 + tx];
  __syncthreads();
#pragma unroll
  for (int i = 0; i < 4; i++)
    Wt[(size_t)(n0 + ty + 8*i) * E_ + k0 + tx] = __float2bfloat16(tile[tx][ty + 8*i]);
}

// ---------------- GEMM: C[M=4096][N] = A[M][K] * Bt[N][K]^T ----------------
// mode 2: N=1024, write f32 + bias to row-major [M][E]  (final output)
// mode 3: N=3072 fused QKV. cols [0,1024)->Q bf16 [BH][T][D] *scale,
//         [1024,2048)->K bf16 [BH][T][D], [2048,3072)->V bf16 [BH][D][T].
//         out base = Q; K at +PROJ_ELEMS; V at +2*PROJ_ELEMS.
__global__ __launch_bounds__(256) void gemm_bt_kernel(
    const bf16* __restrict__ A, const bf16* __restrict__ Bt,
    void* __restrict__ out, const float* __restrict__ bias,
    const int mode, const float scale)
{
  constexpr int K = E_;
  __shared__ __align__(16) bf16 As[128*32];
  __shared__ __align__(16) bf16 Bs[128*32];
  const int tid = threadIdx.x;
  const int w = tid >> 6, l = tid & 63;
  const int lc = l & 15, lr = l >> 4;
  const int m0 = blockIdx.y * 128, n0 = blockIdx.x * 128;
  const int wr = (w >> 1) * 64, wc = (w & 1) * 64;

  f32x4 acc[4][4];
#pragma unroll
  for (int m = 0; m < 4; m++)
#pragma unroll
    for (int n = 0; n < 4; n++) acc[m][n] = (f32x4)0.0f;

  const int srow = l >> 2;            // 0..15
  const int scol = (l & 3) * 8;       // k element offset

  for (int k0 = 0; k0 < K; k0 += 32) {
#pragma unroll
    for (int p = 0; p < 2; p++) {
      const int r = (w*2 + p) * 16 + srow;
      gload_lds16(A  + (size_t)(m0 + r) * K + k0 + scol, &As[(w*2 + p) * 512]);
      gload_lds16(Bt + (size_t)(n0 + r) * K + k0 + scol, &Bs[(w*2 + p) * 512]);
    }
    __syncthreads();
    bf16x8 af[4], bfr[4];
#pragma unroll
    for (int m = 0; m < 4; m++)
      af[m] = *reinterpret_cast<const bf16x8*>(&As[(wr + m*16 + lc) * 32 + lr * 8]);
#pragma unroll
    for (int n = 0; n < 4; n++)
      bfr[n] = *reinterpret_cast<const bf16x8*>(&Bs[(wc + n*16 + lc) * 32 + lr * 8]);
#pragma unroll
    for (int m = 0; m < 4; m++)
#pragma unroll
      for (int n = 0; n < 4; n++)
        acc[m][n] = MFMA16(af[m], bfr[n], acc[m][n]);
    __syncthreads();
  }

  const int proj = blockIdx.x >> 3;   // uniform per block (mode 3)
#pragma unroll
  for (int m = 0; m < 4; m++) {
#pragma unroll
    for (int n = 0; n < 4; n++) {
#pragma unroll
      for (int j = 0; j < 4; j++) {
        const int row = m0 + wr + m*16 + lr*4 + j;   // token index
        const int col = n0 + wc + n*16 + lc;         // output feature
        if (mode == 2) {
          reinterpret_cast<float*>(out)[(size_t)row * E_ + col] = acc[m][n][j] + bias[col];
        } else {
          const int cp = col & (E_-1);
          const int b = row >> 11, t = row & (T_-1);
          const int h = cp >> 6,  d = cp & (D_-1);
          const float v = acc[m][n][j] * (proj == 0 ? scale : 1.0f);
          size_t idx;
          if (proj == 2) idx = (((size_t)(b*H_ + h)) * D_ + d) * T_ + t;      // V transposed
          else           idx = (((size_t)(b*H_ + h)) * T_ + t) * D_ + d;      // Q, K
          reinterpret_cast<bf16*>(out)[proj * PROJ_ELEMS + idx] = __float2bfloat16(v);
        }
      }
    }
  }
}

// ---------------- flash attention (causal) ----------------
// Q,K: [B*H][T][D] bf16 (Q pre-scaled by D^-0.5 * log2(e)). Vt: [B*H][D][T] bf16.
// O: [B*T][E] bf16.
// 4096 independent waves, 16 q-rows each. Blocks ordered largest-work-first.
__global__ __launch_bounds__(256, 4) void attn_fwd_kernel(
    const bf16* __restrict__ Q, const bf16* __restrict__ Kt,
    const bf16* __restrict__ Vt, bf16* __restrict__ O)
{
  __shared__ __align__(16) bf16 P[4][16 * 80];   // per-wave P tile, padded stride 80
  const int tid = threadIdx.x;
  const int w = tid >> 6, l = tid & 63;
  const int lc = l & 15, lr = l >> 4;
  // block bb: p = bb>>5 selects work level (descending), bh = bb&31
  const int bb = blockIdx.x;
  const int p = bb >> 5, bh = bb & 31;
  const int qt = (124 - 4*p) + w;            // 0..127, all covered once
  const int q0 = qt * 16;

  const bf16* Qb = Q  + (size_t)bh * T_ * D_;
  const bf16* Kb = Kt + (size_t)bh * T_ * D_;
  const bf16* Vb = Vt + (size_t)bh * D_ * T_;

  // Q fragments (held across the k loop)
  bf16x8 qf[2];
#pragma unroll
  for (int kk = 0; kk < 2; kk++)
    qf[kk] = *reinterpret_cast<const bf16x8*>(
        &Qb[(size_t)(q0 + lc) * D_ + kk*32 + lr*8]);

  f32x4 oacc[4];
  float mrow[4], lrow[4];
#pragma unroll
  for (int n = 0; n < 4; n++) oacc[n] = (f32x4)0.0f;
#pragma unroll
  for (int j = 0; j < 4; j++) { mrow[j] = -1e30f; lrow[j] = 0.0f; }

  const int nkt = (q0 >> 6) + 1;
  for (int kt = 0; kt < nkt; kt++) {
    const int kbase = kt * 64;
    // ---- S = Q K^T ----
    bf16x8 kf[4][2];
#pragma unroll
    for (int n = 0; n < 4; n++)
#pragma unroll
      for (int kk = 0; kk < 2; kk++)
        kf[n][kk] = *reinterpret_cast<const bf16x8*>(
            &Kb[(size_t)(kbase + n*16 + lc) * D_ + kk*32 + lr*8]);
    f32x4 s[4];
#pragma unroll
    for (int n = 0; n < 4; n++) s[n] = (f32x4)0.0f;
#pragma unroll
    for (int n = 0; n < 4; n++)
#pragma unroll
      for (int kk = 0; kk < 2; kk++)
        s[n] = MFMA16(qf[kk], kf[n][kk], s[n]);

    // ---- hoist V loads so they overlap softmax VALU/TRANS ----
    bf16x8 vf[2][4];
#pragma unroll
    for (int kk = 0; kk < 2; kk++)
#pragma unroll
      for (int n = 0; n < 4; n++)
        vf[kk][n] = *reinterpret_cast<const bf16x8*>(
            &Vb[(size_t)(n*16 + lc) * T_ + kbase + kk*32 + lr*8]);

    // ---- causal mask (log2e*scale folded into Q) ----
    if (kbase + 63 > q0) {
#pragma unroll
      for (int n = 0; n < 4; n++)
#pragma unroll
        for (int j = 0; j < 4; j++) {
          const int q = q0 + lr*4 + j;
          const int k = kbase + n*16 + lc;
          if (k > q) s[n][j] = -1e30f;
        }
    }

    // ---- row max ----
    float pmax[4];
#pragma unroll
    for (int j = 0; j < 4; j++)
      pmax[j] = fmaxf(fmaxf(s[0][j], s[1][j]), fmaxf(s[2][j], s[3][j]));
#pragma unroll
    for (int d = 1; d < 16; d <<= 1)
#pragma unroll
      for (int j = 0; j < 4; j++)
        pmax[j] = fmaxf(pmax[j], __shfl_xor(pmax[j], d));

    // ---- online softmax update (base-2 domain) ----
    float fsc[4];
#pragma unroll
    for (int j = 0; j < 4; j++) {
      const float mn = fmaxf(mrow[j], pmax[j]);
      fsc[j] = exp2f(mrow[j] - mn);
      mrow[j] = mn;
    }
    float psum[4];
#pragma unroll
    for (int j = 0; j < 4; j++) psum[j] = 0.0f;
#pragma unroll
    for (int n = 0; n < 4; n++)
#pragma unroll
      for (int j = 0; j < 4; j++) {
        const float pv = exp2f(s[n][j] - mrow[j]);
        s[n][j] = pv;
        psum[j] += pv;
      }
#pragma unroll
    for (int d = 1; d < 16; d <<= 1)
#pragma unroll
      for (int j = 0; j < 4; j++)
        psum[j] += __shfl_xor(psum[j], d);
#pragma unroll
    for (int j = 0; j < 4; j++)
      lrow[j] = lrow[j] * fsc[j] + psum[j];
#pragma unroll
    for (int n = 0; n < 4; n++)
#pragma unroll
      for (int j = 0; j < 4; j++)
        oacc[n][j] *= fsc[j];

    // ---- P -> LDS (per-wave private, no barrier needed) ----
#pragma unroll
    for (int n = 0; n < 4; n++)
#pragma unroll
      for (int j = 0; j < 4; j++)
        P[w][(lr*4 + j) * 80 + n*16 + lc] = __float2bfloat16(s[n][j]);

    // ---- O += P V ----
#pragma unroll
    for (int kk = 0; kk < 2; kk++) {
      bf16x8 pa = *reinterpret_cast<const bf16x8*>(&P[w][lc * 80 + kk*32 + lr*8]);
#pragma unroll
      for (int n = 0; n < 4; n++)
        oacc[n] = MFMA16(pa, vf[kk][n], oacc[n]);
    }
  }

  // ---- epilogue: O[b*T + q][h*64 + d] ----
  const int b = bh >> 4, h = bh & 15;
#pragma unroll
  for (int j = 0; j < 4; j++) {
    const float inv = 1.0f / lrow[j];
    const int row = b * T_ + q0 + lr*4 + j;
#pragma unroll
    for (int n = 0; n < 4; n++) {
      const int col = h * 64 + n*16 + lc;
      O[(size_t)row * E_ + col] = __float2bfloat16(oacc[n][j] * inv);
    }
  }
}

// ---------------- launch ----------------
extern "C" void kernel_launch(void* const* d_in, const int* in_sizes, int n_in,
                              void* d_out, int out_size, void* d_ws, size_t ws_size,
                              hipStream_t stream) {
  const float* x  = (const float*)d_in[0];
  const float* Wq = (const float*)d_in[1];
  const float* Wk = (const float*)d_in[2];
  const float* Wv = (const float*)d_in[3];
  const float* Wo = (const float*)d_in[4];
  const float* bo = (const float*)d_in[5];
  float* out = (float*)d_out;

  char* ws = (char*)d_ws;
  bf16* xb  = (bf16*)(ws);                         // 8 MB  [4096][1024]
  bf16* WqT = (bf16*)(ws + (8ull  << 20));         // 2 MB  [N][K]  (Wq|Wk|Wv contiguous)
  bf16* WkT = (bf16*)(ws + (10ull << 20));
  bf16* WvT = (bf16*)(ws + (12ull << 20));
  bf16* WoT = (bf16*)(ws + (14ull << 20));
  bf16* Qb  = (bf16*)(ws + (16ull << 20));         // 8 MB [BH][T][D]; K,V follow contiguous
  bf16* Ob  = (bf16*)(ws + (40ull << 20));         // 8 MB  [4096][1024]

  cvt_x_kernel<<<4096, 256, 0, stream>>>(x, xb);
  transpose_cvt4_kernel<<<dim3(32, 32, 4), dim3(32, 8), 0, stream>>>(
      Wq, Wk, Wv, Wo, WqT, WkT, WvT, WoT);

  // fused QKV projection: N = 3072, Bt = [WqT|WkT|WvT] contiguous
  const float qscale = 0.125f * 1.44269504f;       // D^-0.5 * log2(e)
  gemm_bt_kernel<<<dim3(24, 32), 256, 0, stream>>>(xb, WqT, Qb, nullptr, 3, qscale);

  attn_fwd_kernel<<<1024, 256, 0, stream>>>(
      Qb, Qb + PROJ_ELEMS, Qb + 2*PROJ_ELEMS, Ob);

  gemm_bt_kernel<<<dim3(8, 32), 256, 0, stream>>>(Ob, WoT, out, bo, 2, 1.0f);
}